// Round 10
// baseline (187.204 us; speedup 1.0000x reference)
//
#include <hip/hip_runtime.h>

// RecurrentDecoder: B=8192, T=100, I=30, H=100.
// Fused transpose-free LSTM, fp16 MFMA (16x16x32), per-gate column blocks.
// R10: 256 blocks x 256 threads, 1 wave/SIMD, each wave runs TWO independent
// batch-tiles (X=rows 0-15, Y=rows 16-31) sharing register-resident W frags.
// 64 MFMAs/step ks-outer over both tiles (16-way ILP); acts of X hide MFMA_Y
// latency and vice versa. po via W_d in dead col 98; merged-rcp cell;
// no VMEM in step loop; one barrier per step.

#define LOG2E 1.44269504088896340736f

typedef _Float16 f16x8 __attribute__((ext_vector_type(8)));
typedef float    f32x4 __attribute__((ext_vector_type(4)));

__device__ __forceinline__ float rcp_(float x) { return __builtin_amdgcn_rcpf(x); }
__device__ __forceinline__ float exp2_(float x) { return __builtin_amdgcn_exp2f(x); }

__device__ __forceinline__ unsigned pk_f16(float a, float b) {
    return __builtin_bit_cast(unsigned, __builtin_amdgcn_cvt_pkrtz(a, b));
}

#define KS 136   // f16 k-stride (272 B, 16B-aligned)

__global__ __launch_bounds__(256, 1) void lstm_kernel(
    const float* __restrict__ x, const float* __restrict__ Wih,
    const float* __restrict__ Whh, const float* __restrict__ bih,
    const float* __restrict__ bhh, const float* __restrict__ Wd,
    const float* __restrict__ bd, float* __restrict__ out)
{
    __shared__ __align__(16) _Float16 Wstg[128 * KS];     // 34816 B
    __shared__ __align__(16) _Float16 hlds[2][32 * KS];   // 17408 B (dbuf, 32 rows)
    __shared__ float outb[32 * 100];                      // 12800 B
    // total ~65 KB; 1 block/CU (reg-bound anyway)

    const int tid = threadIdx.x;
    const int w   = tid >> 6;      // wave 0..3 -> unit-cols w*32..w*32+31
    const int l   = tid & 63;
    const int g   = l >> 4;        // 0..3 -> rows 4g..4g+3 within tile
    const int c   = l & 15;
    const int b0  = blockIdx.x * 32;
    const bool wpo = (w == 3) && (c == 2);   // owner of po column (col 98)

    // ---- zero LDS (covers all padding; h(-1)=0) ----
    for (int i = tid; i < 128 * KS / 2; i += 256) ((unsigned*)Wstg)[i] = 0u;
    for (int i = tid; i < 2 * 32 * KS / 2; i += 256) ((unsigned*)&hlds[0][0])[i] = 0u;
    __syncthreads();

    // ---- chunked W staging (one gate per chunk), pre-scaled; interleaved
    //      unit->col permutation: col = 32*(u>>5) + 16*(u&1) + ((u&31)>>1)
    //      (lane (w,c) of tile nt holds unit u = w*32 + 2c + nt).
    //      Dead col 98 of s=0 block holds W_d UNSCALED -> MFMA computes po. ----
    f16x8 wfrag[2][4][4];
    for (int s = 0; s < 4; ++s) {
        const float sc = (s == 2) ? (-2.0f * LOG2E) : (-LOG2E);
        for (int idx = tid; idx < 10000; idx += 256) {
            int uu = idx / 100, k = idx - uu * 100;
            int col = 32 * (uu >> 5) + 16 * (uu & 1) + ((uu & 31) >> 1);
            Wstg[col * KS + k] = (_Float16)(Whh[(s * 100 + uu) * 100 + k] * sc);
        }
        if (s == 0)
            for (int k = tid; k < 100; k += 256)
                Wstg[98 * KS + k] = (_Float16)Wd[k];
        __syncthreads();
        #pragma unroll
        for (int nt = 0; nt < 2; ++nt)
            #pragma unroll
            for (int ks = 0; ks < 4; ++ks)
                wfrag[nt][s][ks] = *(const f16x8*)
                    &Wstg[(w * 32 + nt * 16 + c) * KS + ks * 32 + g * 8];
        __syncthreads();
    }

    // ---- xq for both tiles: pre-scaled gate pre-acts from x (+bias) ----
    f32x4 xqX[2][4], xqY[2][4];
    float cregX[2][4], cregY[2][4];
    #pragma unroll
    for (int nt = 0; nt < 2; ++nt) {
        #pragma unroll
        for (int s = 0; s < 4; ++s) {
            xqX[nt][s] = (f32x4){0.f, 0.f, 0.f, 0.f};
            xqY[nt][s] = (f32x4){0.f, 0.f, 0.f, 0.f};
        }
        #pragma unroll
        for (int r = 0; r < 4; ++r) { cregX[nt][r] = 0.0f; cregY[nt][r] = 0.0f; }
    }
    for (int k = 0; k < 30; ++k) {
        float xvX[4], xvY[4];
        #pragma unroll
        for (int r = 0; r < 4; ++r) {
            xvX[r] = x[(b0 + 4 * g + r) * 30 + k];
            xvY[r] = x[(b0 + 16 + 4 * g + r) * 30 + k];
        }
        #pragma unroll
        for (int nt = 0; nt < 2; ++nt) {
            int u = w * 32 + 2 * c + nt;
            if (u < 100) {
                #pragma unroll
                for (int s = 0; s < 4; ++s) {
                    float wv = Wih[(s * 100 + u) * 30 + k];
                    #pragma unroll
                    for (int r = 0; r < 4; ++r) {
                        xqX[nt][s][r] += xvX[r] * wv;
                        xqY[nt][s][r] += xvY[r] * wv;
                    }
                }
            }
        }
    }
    #pragma unroll
    for (int nt = 0; nt < 2; ++nt) {
        int u = w * 32 + 2 * c + nt;
        if (u < 100) {
            #pragma unroll
            for (int s = 0; s < 4; ++s) {
                float sc = (s == 2) ? (-2.0f * LOG2E) : (-LOG2E);
                float b  = bih[s * 100 + u] + bhh[s * 100 + u];
                #pragma unroll
                for (int r = 0; r < 4; ++r) {
                    xqX[nt][s][r] = (xqX[nt][s][r] + b) * sc;
                    xqY[nt][s][r] = (xqY[nt][s][r] + b) * sc;
                }
            }
        }
    }
    const float bdv = bd[0];
    __syncthreads();

    const int afbX = c * KS + g * 8;          // tile X A-frag base (+ks*32)
    const int afbY = (16 + c) * KS + g * 8;   // tile Y
    const int hwc  = w * 32 + 2 * c;          // packed h channel pair

    // activations for one tile (merged-rcp cell: 5 exp2 + 2 rcp per cell)
#define TILE_ACTS(ACC, CREG, HW, ROWOFF)                                       \
    _Pragma("unroll")                                                          \
    for (int r = 0; r < 4; ++r) {                                              \
        float hv[2];                                                           \
        _Pragma("unroll")                                                      \
        for (int nt = 0; nt < 2; ++nt) {                                       \
            float A  = exp2_(ACC[nt][0][r]);                                   \
            float F  = exp2_(ACC[nt][1][r]);                                   \
            float G  = exp2_(ACC[nt][2][r]);                                   \
            float O  = exp2_(ACC[nt][3][r]);                                   \
            float a1 = 1.0f + A, f1 = 1.0f + F;                                \
            float g1 = 1.0f + G, gm = 1.0f - G;                                \
            float ag  = a1 * g1;                                               \
            float num = fmaf(CREG[nt][r], ag, gm * f1);                        \
            float cg  = num * rcp_(ag * f1);                                   \
            CREG[nt][r] = cg;                                                  \
            float C2 = exp2_(cg * (-2.0f * LOG2E));                            \
            hv[nt] = (1.0f - C2) * rcp_((1.0f + O) * (1.0f + C2));             \
        }                                                                      \
        *(unsigned*)&HW[((ROWOFF) + 4 * g + r) * KS + hwc] = pk_f16(hv[0], hv[1]); \
    }

#define STEP(P, TCUR)                                                          \
    {                                                                          \
        const _Float16* hr = &hlds[(P)][0];                                    \
        _Float16*       hw = &hlds[(P) ^ 1][0];                                \
        f16x8 afX[4], afY[4];                                                  \
        _Pragma("unroll")                                                      \
        for (int ks = 0; ks < 4; ++ks) {                                       \
            afX[ks] = *(const f16x8*)&hr[afbX + ks * 32];                      \
            afY[ks] = *(const f16x8*)&hr[afbY + ks * 32];                      \
        }                                                                      \
        f32x4 accX[2][4], accY[2][4];                                          \
        _Pragma("unroll")                                                      \
        for (int nt = 0; nt < 2; ++nt)                                         \
            _Pragma("unroll")                                                  \
            for (int s = 0; s < 4; ++s) {                                      \
                accX[nt][s] = __builtin_amdgcn_mfma_f32_16x16x32_f16(          \
                        afX[0], wfrag[nt][s][0], xqX[nt][s], 0, 0, 0);         \
                accY[nt][s] = __builtin_amdgcn_mfma_f32_16x16x32_f16(          \
                        afY[0], wfrag[nt][s][0], xqY[nt][s], 0, 0, 0);         \
            }                                                                  \
        _Pragma("unroll")                                                      \
        for (int ks = 1; ks < 4; ++ks)                                         \
            _Pragma("unroll")                                                  \
            for (int nt = 0; nt < 2; ++nt)                                     \
                _Pragma("unroll")                                              \
                for (int s = 0; s < 4; ++s) {                                  \
                    accX[nt][s] = __builtin_amdgcn_mfma_f32_16x16x32_f16(      \
                            afX[ks], wfrag[nt][s][ks], accX[nt][s], 0, 0, 0);  \
                    accY[nt][s] = __builtin_amdgcn_mfma_f32_16x16x32_f16(      \
                            afY[ks], wfrag[nt][s][ks], accY[nt][s], 0, 0, 0);  \
                }                                                              \
        if ((TCUR) > 0 && wpo) {                                               \
            _Pragma("unroll")                                                  \
            for (int r = 0; r < 4; ++r) {                                      \
                outb[(4 * g + r) * 100 + (TCUR) - 1] = accX[0][0][r] + bdv;    \
                outb[(16 + 4 * g + r) * 100 + (TCUR) - 1] = accY[0][0][r] + bdv; \
            }                                                                  \
        }                                                                      \
        TILE_ACTS(accX, cregX, hw, 0)                                          \
        TILE_ACTS(accY, cregY, hw, 16)                                         \
        __syncthreads();                                                       \
    }

    for (int t2 = 0; t2 < 50; ++t2) {
        STEP(0, 2 * t2);
        STEP(1, 2 * t2 + 1);
    }
#undef STEP
#undef TILE_ACTS

    // epilogue: po(99) via one more MFMA pass on final h (in hlds[0])
    {
        f16x8 afX[4], afY[4];
        #pragma unroll
        for (int ks = 0; ks < 4; ++ks) {
            afX[ks] = *(const f16x8*)&hlds[0][afbX + ks * 32];
            afY[ks] = *(const f16x8*)&hlds[0][afbY + ks * 32];
        }
        f32x4 aX = {0.f, 0.f, 0.f, 0.f}, aY = {0.f, 0.f, 0.f, 0.f};
        #pragma unroll
        for (int ks = 0; ks < 4; ++ks) {
            aX = __builtin_amdgcn_mfma_f32_16x16x32_f16(afX[ks], wfrag[0][0][ks], aX, 0, 0, 0);
            aY = __builtin_amdgcn_mfma_f32_16x16x32_f16(afY[ks], wfrag[0][0][ks], aY, 0, 0, 0);
        }
        if (wpo) {
            #pragma unroll
            for (int r = 0; r < 4; ++r) {
                outb[(4 * g + r) * 100 + 99] = aX[r] + bdv;
                outb[(16 + 4 * g + r) * 100 + 99] = aY[r] + bdv;
            }
        }
    }
    __syncthreads();
    for (int i = tid; i < 3200; i += 256)
        out[b0 * 100 + i] = outb[i];
}

extern "C" void kernel_launch(void* const* d_in, const int* in_sizes, int n_in,
                              void* d_out, int out_size, void* d_ws, size_t ws_size,
                              hipStream_t stream) {
    (void)in_sizes; (void)n_in; (void)out_size; (void)d_ws; (void)ws_size;
    const float* x   = (const float*)d_in[0];
    const float* Wih = (const float*)d_in[1];
    const float* Whh = (const float*)d_in[2];
    const float* bih = (const float*)d_in[3];
    const float* bhh = (const float*)d_in[4];
    const float* Wd  = (const float*)d_in[5];
    const float* bd  = (const float*)d_in[6];
    lstm_kernel<<<dim3(256), dim3(256), 0, stream>>>(
        x, Wih, Whh, bih, bhh, Wd, bd, (float*)d_out);
}

// Round 11
// 148.216 us; speedup vs baseline: 1.2630x; 1.2630x over previous
//
#include <hip/hip_runtime.h>

// RecurrentDecoder: B=8192, T=100, I=30, H=100.
// R11: occupancy-4 rebuild. 512 blocks x 512 threads (8 waves), B-tile 16.
// Waves 0-6: one 16-unit tile each (wfrag 64 regs, AGPR); wave 7: dedicated
// po-wave (W_d in dead col 112 -> output via MFMA, no acts). xq lives in LDS
// and is re-read per step directly as the MFMA C-init (no xq registers).
// Target <=128 regs/lane -> 2 blocks/CU -> 4 independent waves/SIMD.
// ks-outer MFMA, merged-rcp cell (7 trans/cell), 1 barrier/step, no in-loop VMEM.

#define LOG2E 1.44269504088896340736f

typedef _Float16 f16x8 __attribute__((ext_vector_type(8)));
typedef float    f32x4 __attribute__((ext_vector_type(4)));

__device__ __forceinline__ float rcp_(float x) { return __builtin_amdgcn_rcpf(x); }
__device__ __forceinline__ float exp2_(float x) { return __builtin_amdgcn_exp2f(x); }

#define KS 136   // f16 k-stride (272 B, 16B-aligned, conflict-free proven)

__global__ __launch_bounds__(512, 4) void lstm_kernel(
    const float* __restrict__ x, const float* __restrict__ Wih,
    const float* __restrict__ Whh, const float* __restrict__ bih,
    const float* __restrict__ bhh, const float* __restrict__ Wd,
    const float* __restrict__ bd, float* __restrict__ out)
{
    __shared__ __align__(16) char smem[128 * KS * 2];      // Wstg(34816) U outb(6400)
    __shared__ __align__(16) _Float16 hlds[2][16 * KS];    //  8704 B (dbuf)
    __shared__ __align__(16) float xq_lds[8 * 4 * 64 * 4]; // 32768 B
    // total 76288 B -> 2 blocks/CU

    _Float16* Wstg = (_Float16*)smem;
    float*    outb = (float*)smem;

    const int tid = threadIdx.x;
    const int w   = tid >> 6;      // wave 0..7
    const int l   = tid & 63;
    const int g   = l >> 4;        // 0..3 -> C rows 4g..4g+3
    const int c   = l & 15;        // col within tile / A row
    const int b0  = blockIdx.x * 16;
    const int u   = w * 16 + c;    // unit (identity map; w==7 -> po wave)

    // ---- zero LDS (padding + h(-1)=0; ch 100-127 stay 0 forever) ----
    for (int i = tid; i < 128 * KS / 2; i += 512) ((unsigned*)Wstg)[i] = 0u;
    for (int i = tid; i < 2 * 16 * KS / 2; i += 512) ((unsigned*)&hlds[0][0])[i] = 0u;
    __syncthreads();

    // ---- chunked W staging (one gate per chunk), pre-scaled, identity cols.
    //      Dead col 112 holds W_d (unscaled) -> wave 7's MFMA computes po. ----
    f16x8 wfrag[4][4];   // [s][ks]; wave 7 uses only wfrag[0][*] (= W_d col)
    for (int s = 0; s < 4; ++s) {
        const float sc = (s == 2) ? (-2.0f * LOG2E) : (-LOG2E);
        for (int idx = tid; idx < 10000; idx += 512) {
            int uu = idx / 100, k = idx - uu * 100;
            Wstg[uu * KS + k] = (_Float16)(Whh[(s * 100 + uu) * 100 + k] * sc);
        }
        if (s == 0)
            for (int k = tid; k < 100; k += 512)
                Wstg[112 * KS + k] = (_Float16)Wd[k];
        __syncthreads();
        if (w < 7) {
            #pragma unroll
            for (int ks = 0; ks < 4; ++ks)
                wfrag[s][ks] = *(const f16x8*)&Wstg[u * KS + ks * 32 + g * 8];
        } else if (s == 0) {
            #pragma unroll
            for (int ks = 0; ks < 4; ++ks)
                wfrag[0][ks] = *(const f16x8*)&Wstg[(112 + c) * KS + ks * 32 + g * 8];
        }
        __syncthreads();
    }

    // ---- xq -> LDS (pre-scaled gate pre-acts incl. bias, C-frag coords) ----
    {
        float xq[4][4];
        #pragma unroll
        for (int s = 0; s < 4; ++s)
            #pragma unroll
            for (int r = 0; r < 4; ++r) xq[s][r] = 0.0f;
        if (w < 7 && u < 100) {
            for (int k = 0; k < 30; ++k) {
                float xv[4];
                #pragma unroll
                for (int r = 0; r < 4; ++r) xv[r] = x[(b0 + 4 * g + r) * 30 + k];
                #pragma unroll
                for (int s = 0; s < 4; ++s) {
                    float wv = Wih[(s * 100 + u) * 30 + k];
                    #pragma unroll
                    for (int r = 0; r < 4; ++r) xq[s][r] += xv[r] * wv;
                }
            }
            #pragma unroll
            for (int s = 0; s < 4; ++s) {
                float sc = (s == 2) ? (-2.0f * LOG2E) : (-LOG2E);
                float b  = bih[s * 100 + u] + bhh[s * 100 + u];
                #pragma unroll
                for (int r = 0; r < 4; ++r) xq[s][r] = (xq[s][r] + b) * sc;
            }
        }
        #pragma unroll
        for (int s = 0; s < 4; ++s) {
            f32x4 v = {xq[s][0], xq[s][1], xq[s][2], xq[s][3]};
            *(f32x4*)&xq_lds[(w * 4 + s) * 256 / 4 * 4 + l * 4 + 0] = v;  // see xqb below
        }
    }
    const float bdv = bd[0];
    float creg[4] = {0.f, 0.f, 0.f, 0.f};
    __syncthreads();

    const int afb = c * KS + g * 8;          // A-frag base (+ks*32)
    const int xqb = w * 1024 + l * 4;        // xq_lds word base (+s*256)
    const int hwb = u;                       // h channel (+row*KS)

    // one LSTM step; P = buffer parity (compile-time), TCUR = step index
#define STEP(P, TCUR)                                                         \
    {                                                                         \
        const _Float16* hr = &hlds[(P)][0];                                   \
        _Float16*       hw = &hlds[(P) ^ 1][0];                               \
        f16x8 af[4];                                                          \
        _Pragma("unroll")                                                     \
        for (int ks = 0; ks < 4; ++ks)                                        \
            af[ks] = *(const f16x8*)&hr[afb + ks * 32];                       \
        if (w < 7) {                                                          \
            f32x4 acc[4];                                                     \
            _Pragma("unroll")                                                 \
            for (int s = 0; s < 4; ++s)                                       \
                acc[s] = *(const f32x4*)&xq_lds[xqb + s * 256];               \
            _Pragma("unroll")                                                 \
            for (int ks = 0; ks < 4; ++ks)                                    \
                _Pragma("unroll")                                             \
                for (int s = 0; s < 4; ++s)                                   \
                    acc[s] = __builtin_amdgcn_mfma_f32_16x16x32_f16(          \
                            af[ks], wfrag[s][ks], acc[s], 0, 0, 0);           \
            _Pragma("unroll")                                                 \
            for (int r = 0; r < 4; ++r) {                                     \
                float A  = exp2_(acc[0][r]);                                  \
                float F  = exp2_(acc[1][r]);                                  \
                float G  = exp2_(acc[2][r]);                                  \
                float O  = exp2_(acc[3][r]);                                  \
                float a1 = 1.0f + A, f1 = 1.0f + F;                           \
                float g1 = 1.0f + G, gm = 1.0f - G;                           \
                float ag  = a1 * g1;                                          \
                float num = fmaf(creg[r], ag, gm * f1);                       \
                float cg  = num * rcp_(ag * f1);                              \
                creg[r] = cg;                                                 \
                float C2 = exp2_(cg * (-2.0f * LOG2E));                       \
                float hv = (1.0f - C2) * rcp_((1.0f + O) * (1.0f + C2));      \
                hw[(4 * g + r) * KS + hwb] = (_Float16)hv;                    \
            }                                                                 \
        } else {                                                              \
            f32x4 a = {0.f, 0.f, 0.f, 0.f};                                   \
            _Pragma("unroll")                                                 \
            for (int ks = 0; ks < 4; ++ks)                                    \
                a = __builtin_amdgcn_mfma_f32_16x16x32_f16(                   \
                        af[ks], wfrag[0][ks], a, 0, 0, 0);                    \
            if ((TCUR) > 0 && c == 0) {                                       \
                _Pragma("unroll")                                             \
                for (int r = 0; r < 4; ++r)                                   \
                    outb[(4 * g + r) * 100 + (TCUR) - 1] = a[r] + bdv;        \
            }                                                                 \
        }                                                                     \
        __syncthreads();                                                      \
    }

    for (int t2 = 0; t2 < 50; ++t2) {
        STEP(0, 2 * t2);
        STEP(1, 2 * t2 + 1);
    }
#undef STEP

    // epilogue: po(99) from h(99) (in hlds[0]) by wave 7
    if (w == 7) {
        f16x8 af[4];
        #pragma unroll
        for (int ks = 0; ks < 4; ++ks)
            af[ks] = *(const f16x8*)&hlds[0][afb + ks * 32];
        f32x4 a = {0.f, 0.f, 0.f, 0.f};
        #pragma unroll
        for (int ks = 0; ks < 4; ++ks)
            a = __builtin_amdgcn_mfma_f32_16x16x32_f16(af[ks], wfrag[0][ks], a, 0, 0, 0);
        if (c == 0) {
            #pragma unroll
            for (int r = 0; r < 4; ++r)
                outb[(4 * g + r) * 100 + 99] = a[r] + bdv;
        }
    }
    __syncthreads();

    // coalesced vector write of the block's 16x100 outputs
    {
        f32x4*       o4 = (f32x4*)(out + b0 * 100);
        const f32x4* s4 = (const f32x4*)outb;
        for (int i = tid; i < 400; i += 512) o4[i] = s4[i];
    }
}

extern "C" void kernel_launch(void* const* d_in, const int* in_sizes, int n_in,
                              void* d_out, int out_size, void* d_ws, size_t ws_size,
                              hipStream_t stream) {
    (void)in_sizes; (void)n_in; (void)out_size; (void)d_ws; (void)ws_size;
    const float* x   = (const float*)d_in[0];
    const float* Wih = (const float*)d_in[1];
    const float* Whh = (const float*)d_in[2];
    const float* bih = (const float*)d_in[3];
    const float* bhh = (const float*)d_in[4];
    const float* Wd  = (const float*)d_in[5];
    const float* bd  = (const float*)d_in[6];
    lstm_kernel<<<dim3(512), dim3(512), 0, stream>>>(
        x, Wih, Whh, bih, bhh, Wd, bd, (float*)d_out);
}